// Round 1
// baseline (146.587 us; speedup 1.0000x reference)
//
#include <hip/hip_runtime.h>
#include <math.h>

// ---------------------------------------------------------------------------
// Weighted Gaussian-MMD loss (StructuredKernel_79439715107059)
//
// Pipeline (all on `stream`):
//   0. hipMemsetAsync: zero 9 accumulator floats in ws
//   1. weight_kernel : per-point MLP -> raw softplus weight w, scaled pos;
//                      wave-reduced atomics for sum(w), sum(w*x), sum(w*y)
//   2. center_kernel : rewrite float4 {x-mx, y-my, w/sw, 0}
//   3. mmd_kernel    : 3 pairwise terms, j-tile in LDS, 4 i/thread,
//                      block-reduce -> atomicAdd per-term
//   4. final_kernel  : gate MLP + loss*gate + bias -> out[0]
// ---------------------------------------------------------------------------

#define MMD_THREADS 256
#define I_PER_THREAD 4
#define NPTS_PER_BLOCK (MMD_THREADS * I_PER_THREAD)  // 1024 i per block
#define TJ 256                                       // j-tile in LDS

__device__ __forceinline__ float softplusf(float x) {
    // stable: max(x,0) + log1p(exp(-|x|))
    return fmaxf(x, 0.0f) + log1pf(expf(-fabsf(x)));
}

__device__ __forceinline__ float fast_exp2(float x) {
#if __has_builtin(__builtin_amdgcn_exp2f)
    return __builtin_amdgcn_exp2f(x);   // raw v_exp_f32 (1 ulp; flushes underflow to 0 - fine)
#else
    return exp2f(x);
#endif
}

// sums layout (9 floats): [0..2] term accumulators, [3..5] base {sw,swx,swy},
//                         [6..8] target {sw,swx,swy}
__global__ __launch_bounds__(256) void weight_kernel(
    const float* __restrict__ bpos, const float* __restrict__ bfeat,
    const float* __restrict__ tpos, const float* __restrict__ tfeat,
    const float* __restrict__ w1, const float* __restrict__ b1,
    const float* __restrict__ w2, const float* __restrict__ b2,
    const float* __restrict__ log_scale,
    float4* __restrict__ b4, float4* __restrict__ t4,
    float* __restrict__ sums, int n, int m)
{
    int idx = blockIdx.x * 256 + threadIdx.x;
    int total = n + m;
    float w = 0.f, px = 0.f, py = 0.f;
    int cloud = 0;
    if (idx < total) {
        const float* pos; const float* feat; int i;
        if (idx < n) { pos = bpos; feat = bfeat; i = idx; cloud = 0; }
        else         { pos = tpos; feat = tfeat; i = idx - n; cloud = 1; }
        float sx = expf(log_scale[0]);
        float sy = expf(log_scale[1]);
        px = pos[2*i]   * sx;
        py = pos[2*i+1] * sy;
        float f0 = feat[5*i], f1 = feat[5*i+1], f2 = feat[5*i+2],
              f3 = feat[5*i+3], f4 = feat[5*i+4];
        float logit = b2[0];
        #pragma unroll
        for (int h = 0; h < 32; ++h) {           // Linear(5,32)+ReLU -> Linear(32,1)
            float a = b1[h];
            a = fmaf(f0, w1[h],      a);
            a = fmaf(f1, w1[32+h],   a);
            a = fmaf(f2, w1[64+h],   a);
            a = fmaf(f3, w1[96+h],   a);
            a = fmaf(f4, w1[128+h],  a);
            a = fmaxf(a, 0.f);
            logit = fmaf(a, w2[h], logit);
        }
        w = softplusf(logit) + 1e-6f;
        float4 v = make_float4(px, py, w, 0.f);
        if (cloud == 0) b4[i] = v; else t4[i] = v;
    }
    // n,m are multiples of 64 -> cloud is wave-uniform; wave butterfly reduce
    float sw = w, swx = w*px, swy = w*py;
    #pragma unroll
    for (int off = 32; off > 0; off >>= 1) {
        sw  += __shfl_down(sw,  off, 64);
        swx += __shfl_down(swx, off, 64);
        swy += __shfl_down(swy, off, 64);
    }
    if ((threadIdx.x & 63) == 0 && idx < total) {
        float* dst = sums + 3 + cloud * 3;
        atomicAdd(dst + 0, sw);
        atomicAdd(dst + 1, swx);
        atomicAdd(dst + 2, swy);
    }
}

__global__ __launch_bounds__(256) void center_kernel(
    float4* __restrict__ b4, float4* __restrict__ t4,
    const float* __restrict__ sums, int n, int m)
{
    int idx = blockIdx.x * 256 + threadIdx.x;
    int total = n + m;
    if (idx >= total) return;
    int cloud = (idx < n) ? 0 : 1;
    float4* arr = cloud ? t4 : b4;
    int i = cloud ? idx - n : idx;
    const float* s = sums + 3 + cloud * 3;
    float sw = s[0];
    float mx = s[1] / sw, my = s[2] / sw;
    float4 v = arr[i];
    arr[i] = make_float4(v.x - mx, v.y - my, v.z / sw, 0.f);
}

__global__ __launch_bounds__(MMD_THREADS) void mmd_kernel(
    const float4* __restrict__ b4, const float4* __restrict__ t4,
    const float* __restrict__ log_sigma,
    float* __restrict__ sums, int n, int m)
{
    int t = blockIdx.z;
    const float4* X; const float4* Y; int nx, ny;
    if (t == 0)      { X = b4; Y = b4; nx = n; ny = n; }
    else if (t == 1) { X = b4; Y = t4; nx = n; ny = m; }
    else             { X = t4; Y = t4; nx = m; ny = m; }
    float sigma = expf(log_sigma[0]);
    float cexp = -1.4426950408889634f / (2.f * sigma * sigma);  // exp(-d2*inv)=exp2(d2*cexp)

    __shared__ float4 ytile[TJ];
    int j0 = blockIdx.y * TJ;
    for (int j = threadIdx.x; j < TJ; j += MMD_THREADS) {
        int jj = j0 + j;
        ytile[j] = (jj < ny) ? Y[jj] : make_float4(0.f, 0.f, 0.f, 0.f);
    }
    __syncthreads();

    float xi[I_PER_THREAD], yi[I_PER_THREAD], wi[I_PER_THREAD], acc[I_PER_THREAD];
    int ibase = blockIdx.x * NPTS_PER_BLOCK + threadIdx.x;
    #pragma unroll
    for (int s = 0; s < I_PER_THREAD; ++s) {
        int ii = ibase + s * MMD_THREADS;
        float4 v = (ii < nx) ? X[ii] : make_float4(0.f, 0.f, 0.f, 0.f);
        xi[s] = v.x; yi[s] = v.y; wi[s] = v.z; acc[s] = 0.f;
    }
    for (int j = 0; j < TJ; ++j) {
        float4 v = ytile[j];                      // ds_read_b128, wave-broadcast
        #pragma unroll
        for (int s = 0; s < I_PER_THREAD; ++s) {
            float dx = xi[s] - v.x;
            float dy = yi[s] - v.y;
            float d2 = fmaf(dy, dy, dx * dx);
            acc[s] = fmaf(v.z, fast_exp2(d2 * cexp), acc[s]);
        }
    }
    float r = 0.f;
    #pragma unroll
    for (int s = 0; s < I_PER_THREAD; ++s) r = fmaf(wi[s], acc[s], r);

    // block reduce: wave butterfly then cross-wave via LDS
    #pragma unroll
    for (int off = 32; off > 0; off >>= 1) r += __shfl_down(r, off, 64);
    __shared__ float wsum[MMD_THREADS / 64];
    int wid = threadIdx.x >> 6;
    if ((threadIdx.x & 63) == 0) wsum[wid] = r;
    __syncthreads();
    if (threadIdx.x == 0) {
        float tot = 0.f;
        #pragma unroll
        for (int k = 0; k < MMD_THREADS / 64; ++k) tot += wsum[k];
        atomicAdd(&sums[t], tot);
    }
}

__global__ void final_kernel(
    const float* __restrict__ bdesc, const float* __restrict__ tdesc,
    const float* __restrict__ g1, const float* __restrict__ gb1,
    const float* __restrict__ g2, const float* __restrict__ gb2,
    const float* __restrict__ bias, const float* __restrict__ sums,
    float* __restrict__ out)
{
    if (threadIdx.x != 0 || blockIdx.x != 0) return;
    float d0 = fabsf(bdesc[0] - tdesc[0]);
    float d1 = fabsf(bdesc[1] - tdesc[1]);
    float d2 = fabsf(bdesc[2] - tdesc[2]);
    float d3 = fabsf(bdesc[3] - tdesc[3]);
    float logit = gb2[0];
    #pragma unroll
    for (int h = 0; h < 32; ++h) {
        float a = gb1[h];
        a = fmaf(d0, g1[h],      a);
        a = fmaf(d1, g1[32+h],   a);
        a = fmaf(d2, g1[64+h],   a);
        a = fmaf(d3, g1[96+h],   a);
        a = fmaxf(a, 0.f);
        logit = fmaf(a, g2[h], logit);
    }
    float gate = softplusf(logit) + 1e-6f;
    float loss = sums[0] - 2.f * sums[1] + sums[2];
    out[0] = loss * gate + bias[0];
}

extern "C" void kernel_launch(void* const* d_in, const int* in_sizes, int n_in,
                              void* d_out, int out_size, void* d_ws, size_t ws_size,
                              hipStream_t stream)
{
    const float* bpos      = (const float*)d_in[0];
    const float* bfeat     = (const float*)d_in[1];
    const float* bdesc     = (const float*)d_in[2];
    const float* tpos      = (const float*)d_in[3];
    const float* tfeat     = (const float*)d_in[4];
    const float* tdesc     = (const float*)d_in[5];
    const float* w1        = (const float*)d_in[6];
    const float* b1        = (const float*)d_in[7];
    const float* w2        = (const float*)d_in[8];
    const float* b2        = (const float*)d_in[9];
    const float* g1        = (const float*)d_in[10];
    const float* gb1       = (const float*)d_in[11];
    const float* g2        = (const float*)d_in[12];
    const float* gb2       = (const float*)d_in[13];
    const float* log_sigma = (const float*)d_in[14];
    const float* log_scale = (const float*)d_in[15];
    const float* bias      = (const float*)d_in[16];
    float* out = (float*)d_out;

    int n = in_sizes[0] / 2;   // 8192
    int m = in_sizes[3] / 2;   // 8192

    char* ws = (char*)d_ws;
    float4* b4  = (float4*)ws;
    float4* t4  = (float4*)(ws + (size_t)n * sizeof(float4));
    float* sums = (float*)(ws + (size_t)(n + m) * sizeof(float4));  // 9 floats

    hipMemsetAsync(sums, 0, 9 * sizeof(float), stream);

    int total = n + m;
    int wb = (total + 255) / 256;
    weight_kernel<<<wb, 256, 0, stream>>>(bpos, bfeat, tpos, tfeat,
                                          w1, b1, w2, b2, log_scale,
                                          b4, t4, sums, n, m);
    center_kernel<<<wb, 256, 0, stream>>>(b4, t4, sums, n, m);

    int nmax = n > m ? n : m;
    dim3 grid((nmax + NPTS_PER_BLOCK - 1) / NPTS_PER_BLOCK,
              (nmax + TJ - 1) / TJ, 3);
    mmd_kernel<<<grid, MMD_THREADS, 0, stream>>>(b4, t4, log_sigma, sums, n, m);

    final_kernel<<<1, 64, 0, stream>>>(bdesc, tdesc, g1, gb1, g2, gb2,
                                       bias, sums, out);
}